// Round 2
// baseline (537.134 us; speedup 1.0000x reference)
//
#include <hip/hip_runtime.h>
#include <hip/hip_bf16.h>
#include <stdint.h>

// Problem constants
#define NB 32
#define NS 8
#define NT 512
#define NC 128
#define NH 128

typedef __bf16 bf16_t;
typedef bf16_t bf16x8 __attribute__((ext_vector_type(8)));
typedef bf16_t bf16x4 __attribute__((ext_vector_type(4)));
typedef float  f32x4  __attribute__((ext_vector_type(4)));

// ---------------------------------------------------------------------------
// k_split: fp32 -> (hi, lo) bf16 pair, elementwise, float4-vectorized.
// hi = rne_bf16(x); lo = rne_bf16(x - (float)hi). hi+lo carries ~16 mantissa bits.
// ---------------------------------------------------------------------------
__global__ __launch_bounds__(256) void k_split(const float* __restrict__ in,
                                               bf16_t* __restrict__ hi,
                                               bf16_t* __restrict__ lo, int n4) {
  int i = blockIdx.x * 256 + threadIdx.x;
  if (i >= n4) return;
  f32x4 x = ((const f32x4*)in)[i];
  bf16x4 h, l;
#pragma unroll
  for (int j = 0; j < 4; j++) {
    bf16_t hb = (bf16_t)x[j];
    h[j] = hb;
    l[j] = (bf16_t)(x[j] - (float)hb);
  }
  ((bf16x4*)hi)[i] = h;
  ((bf16x4*)lo)[i] = l;
}

// ---------------------------------------------------------------------------
// k_prep_w: transpose + split W[c][h] -> Wt{h,l}[mat][h][c]  (rows contiguous
// in c so MFMA B-fragments are 16B contiguous loads).
// The score scale 128^-0.5 is FOLDED INTO Wq here, so the fused attention
// kernel's QK^T accumulators come out pre-scaled.
// ---------------------------------------------------------------------------
__global__ void k_prep_w(const float* __restrict__ Wq, const float* __restrict__ Wk,
                         const float* __restrict__ Wv, bf16_t* __restrict__ Wth,
                         bf16_t* __restrict__ Wtl) {
  int w = blockIdx.x >> 7;      // matrix 0..2
  int h = blockIdx.x & 127;     // output column
  int c = threadIdx.x;          // input row
  const float* W = (w == 0) ? Wq : (w == 1) ? Wk : Wv;
  float x = W[c * NH + h];
  if (w == 0) x *= 0.08838834764831845f;  // 128^-0.5 folded into Wq
  bf16_t hb = (bf16_t)x;
  int o = (w * 128 + h) * 128 + c;
  Wth[o] = hb;
  Wtl[o] = (bf16_t)(x - (float)hb);
}

// ---------------------------------------------------------------------------
// k_qkv: [B*T,128] x [128,128] NT-MFMA with hi/lo split (fp32-accurate).
// blockIdx.y selects matrix: 0->q, 1->k (written directly as hi/lo bf16 pairs
// for the fused kernel's QK^T), 2->v (bf16, transposed to vt[b][h][u] for the
// PV stage's B-fragments).
// ---------------------------------------------------------------------------
__global__ __launch_bounds__(256) void k_qkv(const bf16_t* __restrict__ xh,
                                             const bf16_t* __restrict__ xl,
                                             const bf16_t* __restrict__ Wth,
                                             const bf16_t* __restrict__ Wtl,
                                             bf16_t* __restrict__ qh,
                                             bf16_t* __restrict__ ql,
                                             bf16_t* __restrict__ kh,
                                             bf16_t* __restrict__ kl,
                                             bf16_t* __restrict__ vt) {
  int mat = blockIdx.y;
  int t0 = blockIdx.x * 64;           // global row over B*T
  int lane = threadIdx.x & 63;
  int wave = threadIdx.x >> 6;
  int l15 = lane & 15;
  int kq = (lane >> 4) * 8;           // quad*8: k offset within 32-wide K-step
  int row = t0 + wave * 16 + l15;
  const bf16_t* Wh = Wth + mat * NC * NH;
  const bf16_t* Wl = Wtl + mat * NC * NH;

  f32x4 zero = {0.f, 0.f, 0.f, 0.f};
  f32x4 acc[8];
#pragma unroll
  for (int i = 0; i < 8; i++) acc[i] = zero;

#pragma unroll
  for (int k0 = 0; k0 < NC; k0 += 32) {
    bf16x8 ah = *(const bf16x8*)(xh + (size_t)row * NC + k0 + kq);
    bf16x8 al = *(const bf16x8*)(xl + (size_t)row * NC + k0 + kq);
#pragma unroll
    for (int nt = 0; nt < 8; nt++) {
      bf16x8 bh = *(const bf16x8*)(Wh + (nt * 16 + l15) * NC + k0 + kq);
      bf16x8 bl = *(const bf16x8*)(Wl + (nt * 16 + l15) * NC + k0 + kq);
      acc[nt] = __builtin_amdgcn_mfma_f32_16x16x32_bf16(ah, bh, acc[nt], 0, 0, 0);
      acc[nt] = __builtin_amdgcn_mfma_f32_16x16x32_bf16(ah, bl, acc[nt], 0, 0, 0);
      acc[nt] = __builtin_amdgcn_mfma_f32_16x16x32_bf16(al, bh, acc[nt], 0, 0, 0);
    }
  }

  int trow = t0 + wave * 16 + (lane >> 4) * 4;  // D-layout: row = quad*4 + reg
  if (mat < 2) {
    bf16_t* dh = (mat == 0) ? qh : kh;
    bf16_t* dl = (mat == 0) ? ql : kl;
#pragma unroll
    for (int nt = 0; nt < 8; nt++) {
      int h = nt * 16 + l15;
#pragma unroll
      for (int r = 0; r < 4; r++) {
        float v = acc[nt][r];
        bf16_t hb = (bf16_t)v;
        dh[(size_t)(trow + r) * NH + h] = hb;
        dl[(size_t)(trow + r) * NH + h] = (bf16_t)(v - (float)hb);
      }
    }
  } else {
    int b = trow >> 9;
    int tl = trow & 511;
#pragma unroll
    for (int nt = 0; nt < 8; nt++) {
      int h = nt * 16 + l15;
      bf16x4 pk;
#pragma unroll
      for (int r = 0; r < 4; r++) pk[r] = (bf16_t)acc[nt][r];
      *(bf16x4*)(vt + ((size_t)b * NH + h) * NT + tl) = pk;  // 8B store, 4 consecutive u
    }
  }
}

// ---------------------------------------------------------------------------
// k_attn v3 (FUSED scores+softmax+PV): block = (b, 16-row t-tile), 512 thr.
//  - QK^T computed IN-KERNEL: wave w owns u-slice [w*64, w*64+64); the 16x64
//    fp32 score tile lives in 16 VGPRs (wacc) for the whole s-loop. k_scores
//    and the 67 MB wei HBM round-trip are deleted.
//  - Pass A loads adj in MFMA-D layout (scalar dword loads, 4x64B segments
//    per instr) so wei never needs a layout change: e = exp(wacc * adj).
//  - p double-buffered in LDS (33 KB; free at 4 blocks/CU) -> 1 barrier per s.
//  - Geometry: grid 32x32 = 1024 blocks = exactly 4 blocks/CU = 32 waves/CU
//    (100% occupancy) under the 64-VGPR budget (__launch_bounds__(512,8)).
//    2x the waves of v2 + 2x the in-flight loads per wave = the latency wall
//    (182 us at ~1.8 TB/s delivered) should halve or better.
//  - Numerics identical: fp32 wei x fp32 adj, __expf, bf16 P, ones-MFMA denom.
// ---------------------------------------------------------------------------
#define PLD 520  // 512 + 8 bf16 pad

__global__ __launch_bounds__(512, 8) void k_attn(const bf16_t* __restrict__ qh,
                                                 const bf16_t* __restrict__ ql,
                                                 const bf16_t* __restrict__ kh,
                                                 const bf16_t* __restrict__ kl,
                                                 const float* __restrict__ adj,
                                                 const bf16_t* __restrict__ vt,
                                                 float* __restrict__ out) {
  __shared__ bf16_t p[2][16 * PLD];
  int t0 = blockIdx.x * 16;
  int b = blockIdx.y;
  int lane = threadIdx.x & 63;
  int wave = threadIdx.x >> 6;  // 0..7
  int l15 = lane & 15;
  int q4 = lane >> 4;           // quad 0..3
  int kq = q4 * 8;
  int u0 = wave * 64;           // this wave's u-slice (QK^T + pass A)
  int h0 = wave * 16;           // this wave's h-slice (PV)

  // ---- QK^T: wacc[nt][r] = wei[t0 + q4*4 + r][u0 + nt*16 + l15] (pre-scaled) ----
  f32x4 zero = {0.f, 0.f, 0.f, 0.f};
  f32x4 wacc[4];
#pragma unroll
  for (int i = 0; i < 4; i++) wacc[i] = zero;
  {
    size_t qb = ((size_t)b * NT + t0 + l15) * NH;
    size_t kb = ((size_t)b * NT + u0 + l15) * NH;
#pragma unroll
    for (int k0 = 0; k0 < NH; k0 += 32) {
      bf16x8 ah = *(const bf16x8*)(qh + qb + k0 + kq);
      bf16x8 al = *(const bf16x8*)(ql + qb + k0 + kq);
#pragma unroll
      for (int nt = 0; nt < 4; nt++) {
        bf16x8 bh = *(const bf16x8*)(kh + kb + (size_t)nt * 16 * NH + k0 + kq);
        bf16x8 bl = *(const bf16x8*)(kl + kb + (size_t)nt * 16 * NH + k0 + kq);
        wacc[nt] = __builtin_amdgcn_mfma_f32_16x16x32_bf16(ah, bh, wacc[nt], 0, 0, 0);
        wacc[nt] = __builtin_amdgcn_mfma_f32_16x16x32_bf16(ah, bl, wacc[nt], 0, 0, 0);
        wacc[nt] = __builtin_amdgcn_mfma_f32_16x16x32_bf16(al, bh, wacc[nt], 0, 0, 0);
      }
    }
  }

  const bf16_t* vb = vt + (size_t)b * NH * NT;
  bf16x8 ones;
#pragma unroll
  for (int j = 0; j < 8; j++) ones[j] = (bf16_t)1.0f;

  for (int s = 0; s < NS; s++) {
    // ---- Pass A: p = exp(wei*adj) for this wave's 16x64 sub-tile ----
    bf16_t* pb = &p[s & 1][0];
    const float* abase =
        adj + (((size_t)b * NS + s) * NT + t0 + q4 * 4) * NT + u0 + l15;
#pragma unroll
    for (int nt = 0; nt < 4; nt++) {
#pragma unroll
      for (int r = 0; r < 4; r++) {
        float a = abase[(size_t)r * NT + nt * 16];
        float e = __expf(wacc[nt][r] * a);
        pb[(q4 * 4 + r) * PLD + u0 + nt * 16 + l15] = (bf16_t)e;
      }
    }
    __syncthreads();  // p[s&1] complete. Safe vs stragglers in PV(s-1): they
                      // read p[(s-1)&1], and no wave can reach pass A(s+1)
                      // (which would overwrite it) without this barrier.

    // ---- Pass B: out[t0..+16, h0..+16] = (P @ V) / (P @ 1) ----
    f32x4 acc = zero, accl = zero;
#pragma unroll 4
    for (int k0 = 0; k0 < NT; k0 += 32) {
      bf16x8 afr = *(const bf16x8*)&pb[l15 * PLD + k0 + kq];
      accl = __builtin_amdgcn_mfma_f32_16x16x32_bf16(afr, ones, accl, 0, 0, 0);
      bf16x8 bfr = *(const bf16x8*)(vb + (size_t)(h0 + l15) * NT + k0 + kq);
      acc = __builtin_amdgcn_mfma_f32_16x16x32_bf16(afr, bfr, acc, 0, 0, 0);
    }

    // ---- epilogue ----
    float* obase = out + (((size_t)b * NS + s) * NT + t0) * NH;
#pragma unroll
    for (int r = 0; r < 4; r++) {
      float linv = 1.0f / accl[r];
      obase[(size_t)(q4 * 4 + r) * NH + h0 + l15] = acc[r] * linv;
    }
    // no second barrier: next pass A writes the OTHER p buffer.
  }
}

// ---------------------------------------------------------------------------
extern "C" void kernel_launch(void* const* d_in, const int* in_sizes, int n_in,
                              void* d_out, int out_size, void* d_ws, size_t ws_size,
                              hipStream_t stream) {
  const float* x = (const float*)d_in[0];
  const float* adj = (const float*)d_in[1];
  const float* Wq = (const float*)d_in[2];
  const float* Wk = (const float*)d_in[3];
  const float* Wv = (const float*)d_in[4];
  float* out = (float*)d_out;

  const size_t BTC = (size_t)NB * NT * NC;  // 2,097,152 elements

  // Workspace carve-up (all 16B-aligned chunks); ~29 MB (wei deleted)
  char* base = (char*)d_ws;
  bf16_t* xh = (bf16_t*)base;  base += BTC * 2;
  bf16_t* xl = (bf16_t*)base;  base += BTC * 2;
  bf16_t* Wth = (bf16_t*)base; base += (size_t)3 * NC * NH * 2;
  bf16_t* Wtl = (bf16_t*)base; base += (size_t)3 * NC * NH * 2;
  bf16_t* qh = (bf16_t*)base;  base += BTC * 2;
  bf16_t* ql = (bf16_t*)base;  base += BTC * 2;
  bf16_t* kh = (bf16_t*)base;  base += BTC * 2;
  bf16_t* kl = (bf16_t*)base;  base += BTC * 2;
  bf16_t* vt = (bf16_t*)base;  base += BTC * 2;
  (void)in_sizes; (void)n_in; (void)out_size; (void)ws_size;

  // 1. split x into hi/lo bf16
  k_split<<<(int)(BTC / 4 / 256), 256, 0, stream>>>(x, xh, xl, (int)(BTC / 4));
  // 2. transpose+split W (scale folded into Wq)
  k_prep_w<<<384, 128, 0, stream>>>(Wq, Wk, Wv, Wth, Wtl);
  // 3. q,k -> hi/lo bf16 directly; v -> vt bf16 transposed
  k_qkv<<<dim3((int)(NB * NT / 64), 3), 256, 0, stream>>>(xh, xl, Wth, Wtl,
                                                          qh, ql, kh, kl, vt);
  // 4. fused scores + softmax + PV
  k_attn<<<dim3(NT / 16, NB), 512, 0, stream>>>(qh, ql, kh, kl, adj, vt, out);
}

// Round 3
// 525.062 us; speedup vs baseline: 1.0230x; 1.0230x over previous
//
#include <hip/hip_runtime.h>
#include <hip/hip_bf16.h>
#include <stdint.h>

// Problem constants
#define NB 32
#define NS 8
#define NT 512
#define NC 128
#define NH 128

typedef __bf16 bf16_t;
typedef bf16_t bf16x8 __attribute__((ext_vector_type(8)));
typedef bf16_t bf16x4 __attribute__((ext_vector_type(4)));
typedef float  f32x4  __attribute__((ext_vector_type(4)));

// ---------------------------------------------------------------------------
// k_split: fp32 -> (hi, lo) bf16 pair, elementwise, float4-vectorized.
// hi = rne_bf16(x); lo = rne_bf16(x - (float)hi). hi+lo carries ~16 mantissa bits.
// ---------------------------------------------------------------------------
__global__ __launch_bounds__(256) void k_split(const float* __restrict__ in,
                                               bf16_t* __restrict__ hi,
                                               bf16_t* __restrict__ lo, int n4) {
  int i = blockIdx.x * 256 + threadIdx.x;
  if (i >= n4) return;
  f32x4 x = ((const f32x4*)in)[i];
  bf16x4 h, l;
#pragma unroll
  for (int j = 0; j < 4; j++) {
    bf16_t hb = (bf16_t)x[j];
    h[j] = hb;
    l[j] = (bf16_t)(x[j] - (float)hb);
  }
  ((bf16x4*)hi)[i] = h;
  ((bf16x4*)lo)[i] = l;
}

// ---------------------------------------------------------------------------
// k_prep_w: transpose + split W[c][h] -> Wt{h,l}[mat][h][c]  (rows contiguous
// in c so MFMA B-fragments are 16B contiguous loads).
// The score scale 128^-0.5 is FOLDED INTO Wq here, so the fused attention
// kernel's QK^T accumulators come out pre-scaled.
// ---------------------------------------------------------------------------
__global__ void k_prep_w(const float* __restrict__ Wq, const float* __restrict__ Wk,
                         const float* __restrict__ Wv, bf16_t* __restrict__ Wth,
                         bf16_t* __restrict__ Wtl) {
  int w = blockIdx.x >> 7;      // matrix 0..2
  int h = blockIdx.x & 127;     // output column
  int c = threadIdx.x;          // input row
  const float* W = (w == 0) ? Wq : (w == 1) ? Wk : Wv;
  float x = W[c * NH + h];
  if (w == 0) x *= 0.08838834764831845f;  // 128^-0.5 folded into Wq
  bf16_t hb = (bf16_t)x;
  int o = (w * 128 + h) * 128 + c;
  Wth[o] = hb;
  Wtl[o] = (bf16_t)(x - (float)hb);
}

// ---------------------------------------------------------------------------
// k_qkv: [B*T,128] x [128,128] NT-MFMA with hi/lo split (fp32-accurate).
// blockIdx.y selects matrix: 0->q, 1->k (written directly as hi/lo bf16 pairs
// for the fused kernel's QK^T), 2->v (bf16, transposed to vt[b][h][u] for the
// PV stage's B-fragments).
// ---------------------------------------------------------------------------
__global__ __launch_bounds__(256) void k_qkv(const bf16_t* __restrict__ xh,
                                             const bf16_t* __restrict__ xl,
                                             const bf16_t* __restrict__ Wth,
                                             const bf16_t* __restrict__ Wtl,
                                             bf16_t* __restrict__ qh,
                                             bf16_t* __restrict__ ql,
                                             bf16_t* __restrict__ kh,
                                             bf16_t* __restrict__ kl,
                                             bf16_t* __restrict__ vt) {
  int mat = blockIdx.y;
  int t0 = blockIdx.x * 64;           // global row over B*T
  int lane = threadIdx.x & 63;
  int wave = threadIdx.x >> 6;
  int l15 = lane & 15;
  int kq = (lane >> 4) * 8;           // quad*8: k offset within 32-wide K-step
  int row = t0 + wave * 16 + l15;
  const bf16_t* Wh = Wth + mat * NC * NH;
  const bf16_t* Wl = Wtl + mat * NC * NH;

  f32x4 zero = {0.f, 0.f, 0.f, 0.f};
  f32x4 acc[8];
#pragma unroll
  for (int i = 0; i < 8; i++) acc[i] = zero;

#pragma unroll
  for (int k0 = 0; k0 < NC; k0 += 32) {
    bf16x8 ah = *(const bf16x8*)(xh + (size_t)row * NC + k0 + kq);
    bf16x8 al = *(const bf16x8*)(xl + (size_t)row * NC + k0 + kq);
#pragma unroll
    for (int nt = 0; nt < 8; nt++) {
      bf16x8 bh = *(const bf16x8*)(Wh + (nt * 16 + l15) * NC + k0 + kq);
      bf16x8 bl = *(const bf16x8*)(Wl + (nt * 16 + l15) * NC + k0 + kq);
      acc[nt] = __builtin_amdgcn_mfma_f32_16x16x32_bf16(ah, bh, acc[nt], 0, 0, 0);
      acc[nt] = __builtin_amdgcn_mfma_f32_16x16x32_bf16(ah, bl, acc[nt], 0, 0, 0);
      acc[nt] = __builtin_amdgcn_mfma_f32_16x16x32_bf16(al, bh, acc[nt], 0, 0, 0);
    }
  }

  int trow = t0 + wave * 16 + (lane >> 4) * 4;  // D-layout: row = quad*4 + reg
  if (mat < 2) {
    bf16_t* dh = (mat == 0) ? qh : kh;
    bf16_t* dl = (mat == 0) ? ql : kl;
#pragma unroll
    for (int nt = 0; nt < 8; nt++) {
      int h = nt * 16 + l15;
#pragma unroll
      for (int r = 0; r < 4; r++) {
        float v = acc[nt][r];
        bf16_t hb = (bf16_t)v;
        dh[(size_t)(trow + r) * NH + h] = hb;
        dl[(size_t)(trow + r) * NH + h] = (bf16_t)(v - (float)hb);
      }
    }
  } else {
    int b = trow >> 9;
    int tl = trow & 511;
#pragma unroll
    for (int nt = 0; nt < 8; nt++) {
      int h = nt * 16 + l15;
      bf16x4 pk;
#pragma unroll
      for (int r = 0; r < 4; r++) pk[r] = (bf16_t)acc[nt][r];
      *(bf16x4*)(vt + ((size_t)b * NH + h) * NT + tl) = pk;  // 8B store, 4 consecutive u
    }
  }
}

// ---------------------------------------------------------------------------
// k_attn v4 (fused scores+softmax+PV), geometry tuned for MLP x occupancy:
//  - 256 threads / 4 waves, __launch_bounds__(256,4) -> 128-VGPR budget.
//    (v3's (512,8) forced VGPR=32: only ~2 loads in flight -> every load paid
//    a full congested latency window serially -> 228 us. Bytes-in-flight =
//    waves x batched-loads; the batching term was destroyed.)
//  - Each wave owns a 128-wide u-slice: wacc[8] (32 VGPRs) holds the score
//    tile in registers across all 8 s-iterations. No wei in LDS or HBM.
//  - Pass A: all 32 adj loads batched into av[8][4] registers (one latency
//    window), then exp+store. Loads are MFMA-D-layout scalars (4x64B
//    segments each, byte-exact coverage of the 16x128 sub-tile).
//  - PV: wave owns 32-wide h-slice; unroll 8 keeps ~8 vt loads in flight.
//  - p double-buffered (33 KB): ONE barrier per s. Grid (32,32)=1024 blocks
//    = exactly 4 blocks/CU (LDS 133 KB) = 16 waves/CU.
//  - Numerics identical: fp32 wei x fp32 adj, __expf, bf16 P, ones-MFMA denom.
// ---------------------------------------------------------------------------
#define PLD 520  // 512 + 8 bf16 pad

__global__ __launch_bounds__(256, 4) void k_attn(const bf16_t* __restrict__ qh,
                                                 const bf16_t* __restrict__ ql,
                                                 const bf16_t* __restrict__ kh,
                                                 const bf16_t* __restrict__ kl,
                                                 const float* __restrict__ adj,
                                                 const bf16_t* __restrict__ vt,
                                                 float* __restrict__ out) {
  __shared__ bf16_t p[2][16 * PLD];
  int t0 = blockIdx.x * 16;
  int b = blockIdx.y;
  int lane = threadIdx.x & 63;
  int wave = threadIdx.x >> 6;  // 0..3
  int l15 = lane & 15;
  int q4 = lane >> 4;           // quad 0..3
  int kq = q4 * 8;
  int u0 = wave * 128;          // this wave's u-slice (QK^T + pass A)
  int h0 = wave * 32;           // this wave's h-slice (PV)

  // ---- QK^T: wacc[nt][r] = wei[t0+q4*4+r][u0+nt*16+l15] (pre-scaled) ----
  f32x4 zero = {0.f, 0.f, 0.f, 0.f};
  f32x4 wacc[8];
#pragma unroll
  for (int i = 0; i < 8; i++) wacc[i] = zero;
  {
    size_t qb = ((size_t)b * NT + t0 + l15) * NH;
    size_t kb = ((size_t)b * NT + u0 + l15) * NH;
#pragma unroll
    for (int k0 = 0; k0 < NH; k0 += 32) {
      bf16x8 ah = *(const bf16x8*)(qh + qb + k0 + kq);
      bf16x8 al = *(const bf16x8*)(ql + qb + k0 + kq);
#pragma unroll
      for (int nt = 0; nt < 8; nt++) {
        bf16x8 bh = *(const bf16x8*)(kh + kb + (size_t)nt * 16 * NH + k0 + kq);
        bf16x8 bl = *(const bf16x8*)(kl + kb + (size_t)nt * 16 * NH + k0 + kq);
        wacc[nt] = __builtin_amdgcn_mfma_f32_16x16x32_bf16(ah, bh, wacc[nt], 0, 0, 0);
        wacc[nt] = __builtin_amdgcn_mfma_f32_16x16x32_bf16(ah, bl, wacc[nt], 0, 0, 0);
        wacc[nt] = __builtin_amdgcn_mfma_f32_16x16x32_bf16(al, bh, wacc[nt], 0, 0, 0);
      }
    }
  }

  const bf16_t* vb = vt + (size_t)b * NH * NT;
  bf16x8 ones;
#pragma unroll
  for (int j = 0; j < 8; j++) ones[j] = (bf16_t)1.0f;

  for (int s = 0; s < NS; s++) {
    bf16_t* pb = &p[s & 1][0];

    // ---- Pass A phase 1: batch-load ALL 32 adj scalars into registers ----
    const float* ab =
        adj + (((size_t)b * NS + s) * NT + t0 + q4 * 4) * NT + u0 + l15;
    float av[8][4];
#pragma unroll
    for (int nt = 0; nt < 8; nt++)
#pragma unroll
      for (int r = 0; r < 4; r++) av[nt][r] = ab[(size_t)r * NT + nt * 16];

    // ---- Pass A phase 2: exp + LDS store ----
#pragma unroll
    for (int nt = 0; nt < 8; nt++)
#pragma unroll
      for (int r = 0; r < 4; r++) {
        float e = __expf(wacc[nt][r] * av[nt][r]);
        pb[(q4 * 4 + r) * PLD + u0 + nt * 16 + l15] = (bf16_t)e;
      }
    __syncthreads();  // p[s&1] complete. Stragglers in PV(s-1) read the OTHER
                      // buffer; overwriting it requires passing barrier(s+1).

    // ---- Pass B: out[t0..+16, h0..+32] = (P @ V) / (P @ 1) ----
    f32x4 acc0 = zero, acc1 = zero, accl = zero;
#pragma unroll 8
    for (int k0 = 0; k0 < NT; k0 += 32) {
      bf16x8 afr = *(const bf16x8*)&pb[l15 * PLD + k0 + kq];
      accl = __builtin_amdgcn_mfma_f32_16x16x32_bf16(afr, ones, accl, 0, 0, 0);
      bf16x8 bfr0 = *(const bf16x8*)(vb + (size_t)(h0 + l15) * NT + k0 + kq);
      bf16x8 bfr1 = *(const bf16x8*)(vb + (size_t)(h0 + 16 + l15) * NT + k0 + kq);
      acc0 = __builtin_amdgcn_mfma_f32_16x16x32_bf16(afr, bfr0, acc0, 0, 0, 0);
      acc1 = __builtin_amdgcn_mfma_f32_16x16x32_bf16(afr, bfr1, acc1, 0, 0, 0);
    }

    // ---- epilogue: divide by row sums, store ----
    float* obase = out + (((size_t)b * NS + s) * NT + t0 + q4 * 4) * NH;
#pragma unroll
    for (int r = 0; r < 4; r++) {
      float linv = 1.0f / accl[r];
      obase[(size_t)r * NH + h0 + l15] = acc0[r] * linv;
      obase[(size_t)r * NH + h0 + 16 + l15] = acc1[r] * linv;
    }
    // no second barrier: next pass A writes the OTHER p buffer.
  }
}

// ---------------------------------------------------------------------------
extern "C" void kernel_launch(void* const* d_in, const int* in_sizes, int n_in,
                              void* d_out, int out_size, void* d_ws, size_t ws_size,
                              hipStream_t stream) {
  const float* x = (const float*)d_in[0];
  const float* adj = (const float*)d_in[1];
  const float* Wq = (const float*)d_in[2];
  const float* Wk = (const float*)d_in[3];
  const float* Wv = (const float*)d_in[4];
  float* out = (float*)d_out;

  const size_t BTC = (size_t)NB * NT * NC;  // 2,097,152 elements

  // Workspace carve-up (all 16B-aligned chunks); ~29 MB (wei deleted)
  char* base = (char*)d_ws;
  bf16_t* xh = (bf16_t*)base;  base += BTC * 2;
  bf16_t* xl = (bf16_t*)base;  base += BTC * 2;
  bf16_t* Wth = (bf16_t*)base; base += (size_t)3 * NC * NH * 2;
  bf16_t* Wtl = (bf16_t*)base; base += (size_t)3 * NC * NH * 2;
  bf16_t* qh = (bf16_t*)base;  base += BTC * 2;
  bf16_t* ql = (bf16_t*)base;  base += BTC * 2;
  bf16_t* kh = (bf16_t*)base;  base += BTC * 2;
  bf16_t* kl = (bf16_t*)base;  base += BTC * 2;
  bf16_t* vt = (bf16_t*)base;  base += BTC * 2;
  (void)in_sizes; (void)n_in; (void)out_size; (void)ws_size;

  // 1. split x into hi/lo bf16
  k_split<<<(int)(BTC / 4 / 256), 256, 0, stream>>>(x, xh, xl, (int)(BTC / 4));
  // 2. transpose+split W (scale folded into Wq)
  k_prep_w<<<384, 128, 0, stream>>>(Wq, Wk, Wv, Wth, Wtl);
  // 3. q,k -> hi/lo bf16 directly; v -> vt bf16 transposed
  k_qkv<<<dim3((int)(NB * NT / 64), 3), 256, 0, stream>>>(xh, xl, Wth, Wtl,
                                                          qh, ql, kh, kl, vt);
  // 4. fused scores + softmax + PV
  k_attn<<<dim3(NT / 16, NB), 256, 0, stream>>>(qh, ql, kh, kl, adj, vt, out);
}

// Round 4
// 442.196 us; speedup vs baseline: 1.2147x; 1.1874x over previous
//
#include <hip/hip_runtime.h>
#include <hip/hip_bf16.h>
#include <stdint.h>

// Problem constants
#define NB 32
#define NS 8
#define NT 512
#define NC 128
#define NH 128

typedef __bf16 bf16_t;
typedef bf16_t bf16x8 __attribute__((ext_vector_type(8)));
typedef bf16_t bf16x4 __attribute__((ext_vector_type(4)));
typedef float  f32x4  __attribute__((ext_vector_type(4)));

// async global->LDS DMA, width 4 (one dword per lane). Per-lane GLOBAL addr,
// wave-uniform LDS base (HW writes base + lane*4). Tracked by vmcnt only —
// zero VGPR cost, scheduler cannot serialize it against uses.
#define GLOAD_LDS4(gp, lp)                                             \
  __builtin_amdgcn_global_load_lds(                                    \
      (const __attribute__((address_space(1))) uint32_t*)(gp),         \
      (__attribute__((address_space(3))) uint32_t*)(lp), 4, 0, 0)

// ---------------------------------------------------------------------------
// k_split: fp32 -> (hi, lo) bf16 pair, elementwise, float4-vectorized.
// ---------------------------------------------------------------------------
__global__ __launch_bounds__(256) void k_split(const float* __restrict__ in,
                                               bf16_t* __restrict__ hi,
                                               bf16_t* __restrict__ lo, int n4) {
  int i = blockIdx.x * 256 + threadIdx.x;
  if (i >= n4) return;
  f32x4 x = ((const f32x4*)in)[i];
  bf16x4 h, l;
#pragma unroll
  for (int j = 0; j < 4; j++) {
    bf16_t hb = (bf16_t)x[j];
    h[j] = hb;
    l[j] = (bf16_t)(x[j] - (float)hb);
  }
  ((bf16x4*)hi)[i] = h;
  ((bf16x4*)lo)[i] = l;
}

// ---------------------------------------------------------------------------
// k_prep_w: transpose + split W[c][h] -> Wt{h,l}[mat][h][c]. Score scale
// 128^-0.5 folded into Wq.
// ---------------------------------------------------------------------------
__global__ void k_prep_w(const float* __restrict__ Wq, const float* __restrict__ Wk,
                         const float* __restrict__ Wv, bf16_t* __restrict__ Wth,
                         bf16_t* __restrict__ Wtl) {
  int w = blockIdx.x >> 7;      // matrix 0..2
  int h = blockIdx.x & 127;     // output column
  int c = threadIdx.x;          // input row
  const float* W = (w == 0) ? Wq : (w == 1) ? Wk : Wv;
  float x = W[c * NH + h];
  if (w == 0) x *= 0.08838834764831845f;  // 128^-0.5 folded into Wq
  bf16_t hb = (bf16_t)x;
  int o = (w * 128 + h) * 128 + c;
  Wth[o] = hb;
  Wtl[o] = (bf16_t)(x - (float)hb);
}

// ---------------------------------------------------------------------------
// k_qkv: [B*T,128] x [128,128] NT-MFMA with hi/lo split (fp32-accurate).
// ---------------------------------------------------------------------------
__global__ __launch_bounds__(256) void k_qkv(const bf16_t* __restrict__ xh,
                                             const bf16_t* __restrict__ xl,
                                             const bf16_t* __restrict__ Wth,
                                             const bf16_t* __restrict__ Wtl,
                                             bf16_t* __restrict__ qh,
                                             bf16_t* __restrict__ ql,
                                             bf16_t* __restrict__ kh,
                                             bf16_t* __restrict__ kl,
                                             bf16_t* __restrict__ vt) {
  int mat = blockIdx.y;
  int t0 = blockIdx.x * 64;           // global row over B*T
  int lane = threadIdx.x & 63;
  int wave = threadIdx.x >> 6;
  int l15 = lane & 15;
  int kq = (lane >> 4) * 8;           // quad*8: k offset within 32-wide K-step
  int row = t0 + wave * 16 + l15;
  const bf16_t* Wh = Wth + mat * NC * NH;
  const bf16_t* Wl = Wtl + mat * NC * NH;

  f32x4 zero = {0.f, 0.f, 0.f, 0.f};
  f32x4 acc[8];
#pragma unroll
  for (int i = 0; i < 8; i++) acc[i] = zero;

#pragma unroll
  for (int k0 = 0; k0 < NC; k0 += 32) {
    bf16x8 ah = *(const bf16x8*)(xh + (size_t)row * NC + k0 + kq);
    bf16x8 al = *(const bf16x8*)(xl + (size_t)row * NC + k0 + kq);
#pragma unroll
    for (int nt = 0; nt < 8; nt++) {
      bf16x8 bh = *(const bf16x8*)(Wh + (nt * 16 + l15) * NC + k0 + kq);
      bf16x8 bl = *(const bf16x8*)(Wl + (nt * 16 + l15) * NC + k0 + kq);
      acc[nt] = __builtin_amdgcn_mfma_f32_16x16x32_bf16(ah, bh, acc[nt], 0, 0, 0);
      acc[nt] = __builtin_amdgcn_mfma_f32_16x16x32_bf16(ah, bl, acc[nt], 0, 0, 0);
      acc[nt] = __builtin_amdgcn_mfma_f32_16x16x32_bf16(al, bh, acc[nt], 0, 0, 0);
    }
  }

  int trow = t0 + wave * 16 + (lane >> 4) * 4;  // D-layout: row = quad*4 + reg
  if (mat < 2) {
    bf16_t* dh = (mat == 0) ? qh : kh;
    bf16_t* dl = (mat == 0) ? ql : kl;
#pragma unroll
    for (int nt = 0; nt < 8; nt++) {
      int h = nt * 16 + l15;
#pragma unroll
      for (int r = 0; r < 4; r++) {
        float v = acc[nt][r];
        bf16_t hb = (bf16_t)v;
        dh[(size_t)(trow + r) * NH + h] = hb;
        dl[(size_t)(trow + r) * NH + h] = (bf16_t)(v - (float)hb);
      }
    }
  } else {
    int b = trow >> 9;
    int tl = trow & 511;
#pragma unroll
    for (int nt = 0; nt < 8; nt++) {
      int h = nt * 16 + l15;
      bf16x4 pk;
#pragma unroll
      for (int r = 0; r < 4; r++) pk[r] = (bf16_t)acc[nt][r];
      *(bf16x4*)(vt + ((size_t)b * NH + h) * NT + tl) = pk;  // 8B store
    }
  }
}

// ---------------------------------------------------------------------------
// k_attn v5: fused scores+softmax+PV with ASYNC adj staging (global_load_lds).
//
// Why: v2-v4 all hit a latency wall (~190-230 us) because the compiler's
// scheduler sinks adj loads to their exp uses (~2-3 in flight/wave, VGPR=60
// regardless of launch_bounds). global_load_lds is fire-and-forget DMA:
// in-flight depth costs ZERO VGPRs and cannot be scheduler-serialized.
//
// vmcnt is IN-ORDER, so any later vmem wait would force the DMA to complete.
// Therefore PV must contain no vmem ops: vt is LOOP-INVARIANT across s, so
// each wave hoists its 16-wide h-slice V-fragments into registers once
// (16 x bf16x8 = 64 VGPR). Per s-iteration:
//   vmcnt(0)                      adj(s) landed (per-wave private slice)
//   exp: ds_read adj, exp, ds_write p
//   lgkmcnt(0); issue DMA(s+1)    adj reads retired before overwrite
//   raw s_barrier (NO vmcnt drain -> DMA flies across)
//   PV: pure LDS + MFMA           DMA latency hides here
//   epilogue stores; raw s_barrier (p WAR)
//
// Geometry: 512 thr / 8 waves; wave owns 64-wide u-slice (wacc[4]) and
// 16-wide h-slice. LDS = p[16][520]bf16 (16.6K) + adj 8x[16][66]f32 (33.8K,
// rows padded to 66 floats: conflict-free exp reads; width-4 DMA writes one
// 256B row per instr so padding never crosses a DMA destination).
// Grid (32,32) = 1024 blocks; __launch_bounds__(512,4) -> VGPR<=128 ->
// 2 blocks/CU = 16 waves/CU, each with 4 KB of zero-cost DMA in flight.
// Numerics identical to v4: adj passes through LDS as exact fp32; same
// __expf, bf16 P, ones-MFMA denominator.
// ---------------------------------------------------------------------------
#define PLD 520   // p row pitch: 512 + 8 bf16
#define ALD 66    // adj row pitch in floats: 64 + 2 pad (bank spread)

__global__ __launch_bounds__(512, 4) void k_attn(const bf16_t* __restrict__ qh,
                                                 const bf16_t* __restrict__ ql,
                                                 const bf16_t* __restrict__ kh,
                                                 const bf16_t* __restrict__ kl,
                                                 const float* __restrict__ adj,
                                                 const bf16_t* __restrict__ vt,
                                                 float* __restrict__ out) {
  __shared__ bf16_t pbuf[16 * PLD];
  __shared__ float adj_lds[8 * 16 * ALD];
  int t0 = blockIdx.x * 16;
  int b = blockIdx.y;
  int lane = threadIdx.x & 63;
  int wave = threadIdx.x >> 6;  // 0..7
  int l15 = lane & 15;
  int q4 = lane >> 4;           // quad 0..3
  int kq = q4 * 8;
  int u0 = wave * 64;           // this wave's u-slice (QK^T + exp)
  int h0 = wave * 16;           // this wave's h-slice (PV)
  float* amy = &adj_lds[wave * 16 * ALD];  // this wave's private adj slice

  // ---- issue DMA for adj(s=0) FIRST (latency hides under QK^T) ----
  {
    const float* src = adj + ((size_t)b * NS * NT + t0) * NT + u0;
#pragma unroll
    for (int row = 0; row < 16; row++)
      GLOAD_LDS4(src + (size_t)row * NT + lane, amy + row * ALD);
  }

  // ---- hoist V fragments into registers (loop-invariant across s) ----
  const bf16_t* vb = vt + (size_t)b * NH * NT;
  bf16x8 vtf[16];
#pragma unroll
  for (int k = 0; k < 16; k++)
    vtf[k] = *(const bf16x8*)(vb + (size_t)(h0 + l15) * NT + k * 32 + kq);

  // ---- QK^T: wacc[nt][r] = wei[t0+q4*4+r][u0+nt*16+l15] (pre-scaled) ----
  f32x4 zero = {0.f, 0.f, 0.f, 0.f};
  f32x4 wacc[4];
#pragma unroll
  for (int i = 0; i < 4; i++) wacc[i] = zero;
  {
    size_t qb = ((size_t)b * NT + t0 + l15) * NH;
    size_t kb = ((size_t)b * NT + u0 + l15) * NH;
#pragma unroll
    for (int k0 = 0; k0 < NH; k0 += 32) {
      bf16x8 ah = *(const bf16x8*)(qh + qb + k0 + kq);
      bf16x8 al = *(const bf16x8*)(ql + qb + k0 + kq);
#pragma unroll
      for (int nt = 0; nt < 4; nt++) {
        bf16x8 bh = *(const bf16x8*)(kh + kb + (size_t)nt * 16 * NH + k0 + kq);
        bf16x8 bl = *(const bf16x8*)(kl + kb + (size_t)nt * 16 * NH + k0 + kq);
        wacc[nt] = __builtin_amdgcn_mfma_f32_16x16x32_bf16(ah, bh, wacc[nt], 0, 0, 0);
        wacc[nt] = __builtin_amdgcn_mfma_f32_16x16x32_bf16(ah, bl, wacc[nt], 0, 0, 0);
        wacc[nt] = __builtin_amdgcn_mfma_f32_16x16x32_bf16(al, bh, wacc[nt], 0, 0, 0);
      }
    }
  }

  bf16x8 ones;
#pragma unroll
  for (int j = 0; j < 8; j++) ones[j] = (bf16_t)1.0f;

#pragma unroll 1
  for (int s = 0; s < NS; s++) {
    // ---- adj(s) landed? (per-wave: vmcnt counts only OUR DMA + retired loads)
    asm volatile("s_waitcnt vmcnt(0)" ::: "memory");
    __builtin_amdgcn_sched_barrier(0);

    // ---- exp: p = exp(wacc * adj), bf16, this wave's 16x64 sub-tile ----
#pragma unroll
    for (int nt = 0; nt < 4; nt++)
#pragma unroll
      for (int r = 0; r < 4; r++) {
        float a = amy[(q4 * 4 + r) * ALD + nt * 16 + l15];
        float e = __expf(wacc[nt][r] * a);
        pbuf[(q4 * 4 + r) * PLD + u0 + nt * 16 + l15] = (bf16_t)e;
      }

    // ---- adj ds_reads + p ds_writes retired, THEN overwrite adj slice ----
    asm volatile("s_waitcnt lgkmcnt(0)" ::: "memory");
    __builtin_amdgcn_sched_barrier(0);
    if (s + 1 < NS) {
      const float* src = adj + (((size_t)b * NS + s + 1) * NT + t0) * NT + u0;
#pragma unroll
      for (int row = 0; row < 16; row++)
        GLOAD_LDS4(src + (size_t)row * NT + lane, amy + row * ALD);
    }

    // ---- raw barrier: p visible (lgkm drained above); DMA stays in flight
    __builtin_amdgcn_s_barrier();

    // ---- PV: pure LDS + MFMA, zero vmem -> DMA latency hides here ----
    f32x4 acc = zero, accl = zero;
#pragma unroll
    for (int k = 0; k < 16; k++) {
      bf16x8 afr = *(const bf16x8*)&pbuf[l15 * PLD + k * 32 + kq];
      accl = __builtin_amdgcn_mfma_f32_16x16x32_bf16(afr, ones, accl, 0, 0, 0);
      acc = __builtin_amdgcn_mfma_f32_16x16x32_bf16(afr, vtf[k], acc, 0, 0, 0);
    }

    // ---- epilogue: divide by row sums, store ----
    float* obase = out + (((size_t)b * NS + s) * NT + t0 + q4 * 4) * NH;
#pragma unroll
    for (int r = 0; r < 4; r++)
      obase[(size_t)r * NH + h0 + l15] = acc[r] * (1.0f / accl[r]);

    // ---- raw barrier: all waves done reading p before next exp overwrites
    __builtin_amdgcn_s_barrier();
  }
}

// ---------------------------------------------------------------------------
extern "C" void kernel_launch(void* const* d_in, const int* in_sizes, int n_in,
                              void* d_out, int out_size, void* d_ws, size_t ws_size,
                              hipStream_t stream) {
  const float* x = (const float*)d_in[0];
  const float* adj = (const float*)d_in[1];
  const float* Wq = (const float*)d_in[2];
  const float* Wk = (const float*)d_in[3];
  const float* Wv = (const float*)d_in[4];
  float* out = (float*)d_out;

  const size_t BTC = (size_t)NB * NT * NC;  // 2,097,152 elements

  // Workspace carve-up (all 16B-aligned chunks); ~29 MB
  char* base = (char*)d_ws;
  bf16_t* xh = (bf16_t*)base;  base += BTC * 2;
  bf16_t* xl = (bf16_t*)base;  base += BTC * 2;
  bf16_t* Wth = (bf16_t*)base; base += (size_t)3 * NC * NH * 2;
  bf16_t* Wtl = (bf16_t*)base; base += (size_t)3 * NC * NH * 2;
  bf16_t* qh = (bf16_t*)base;  base += BTC * 2;
  bf16_t* ql = (bf16_t*)base;  base += BTC * 2;
  bf16_t* kh = (bf16_t*)base;  base += BTC * 2;
  bf16_t* kl = (bf16_t*)base;  base += BTC * 2;
  bf16_t* vt = (bf16_t*)base;  base += BTC * 2;
  (void)in_sizes; (void)n_in; (void)out_size; (void)ws_size;

  // 1. split x into hi/lo bf16
  k_split<<<(int)(BTC / 4 / 256), 256, 0, stream>>>(x, xh, xl, (int)(BTC / 4));
  // 2. transpose+split W (scale folded into Wq)
  k_prep_w<<<384, 128, 0, stream>>>(Wq, Wk, Wv, Wth, Wtl);
  // 3. q,k -> hi/lo bf16 directly; v -> vt bf16 transposed
  k_qkv<<<dim3((int)(NB * NT / 64), 3), 256, 0, stream>>>(xh, xl, Wth, Wtl,
                                                          qh, ql, kh, kl, vt);
  // 4. fused scores + softmax + PV with async adj staging
  k_attn<<<dim3(NT / 16, NB), 512, 0, stream>>>(qh, ql, kh, kl, adj, vt, out);
}